// Round 1
// baseline (6129.765 us; speedup 1.0000x reference)
//
#include <hip/hip_runtime.h>
#include <cstddef>

#define NN 50000
#define EE 400000
#define BB 64
#define BN_EPS 1e-5f

// ---------------- utility ----------------
__global__ void fill_f32(float* __restrict__ p, int n, float v) {
    int i = blockIdx.x * blockDim.x + threadIdx.x;
    if (i < n) p[i] = v;
}

__global__ void deg_edges(const int* __restrict__ ei, float* __restrict__ deg) {
    int e = blockIdx.x * blockDim.x + threadIdx.x;
    if (e < EE) atomicAdd(&deg[ei[EE + e]], 1.0f);
}

__global__ void rsqrt_k(const float* __restrict__ deg, float* __restrict__ dis) {
    int i = blockIdx.x * blockDim.x + threadIdx.x;
    if (i < NN) dis[i] = rsqrtf(deg[i]);
}

// ---------------- fp32 tiled GEMM: C[M,N] = A[M,K] @ B[K,N] ----------------
// BM=BN=64, BK=16, 256 threads, 4x4 per thread.
__global__ __launch_bounds__(256) void gemm_f32(const float* __restrict__ A,
                                                const float* __restrict__ B,
                                                float* __restrict__ C,
                                                int M, int K, int N) {
    __shared__ float As[16][64 + 1];
    __shared__ float Bs[16][64];
    const int tid = threadIdx.x;
    const int tx = tid % 16;          // col group
    const int ty = tid / 16;          // row group
    const int rowBase = blockIdx.y * 64;
    const int colBase = blockIdx.x * 64;

    const int aRow = tid / 4;         // 0..63
    const int aK   = (tid % 4) * 4;   // 0,4,8,12
    const int bK   = tid / 16;        // 0..15
    const int bCol = (tid % 16) * 4;  // 0..60

    float acc[4][4] = {};

    for (int k0 = 0; k0 < K; k0 += 16) {
        int ar = rowBase + aRow;
        float4 av;
        if (ar < M) av = *reinterpret_cast<const float4*>(&A[(size_t)ar * K + k0 + aK]);
        else        av = make_float4(0.f, 0.f, 0.f, 0.f);
        As[aK + 0][aRow] = av.x;
        As[aK + 1][aRow] = av.y;
        As[aK + 2][aRow] = av.z;
        As[aK + 3][aRow] = av.w;

        float4 bv = *reinterpret_cast<const float4*>(&B[(size_t)(k0 + bK) * N + colBase + bCol]);
        *reinterpret_cast<float4*>(&Bs[bK][bCol]) = bv;

        __syncthreads();
#pragma unroll
        for (int k = 0; k < 16; ++k) {
            float a[4], b[4];
#pragma unroll
            for (int m = 0; m < 4; ++m) a[m] = As[k][ty * 4 + m];
#pragma unroll
            for (int n = 0; n < 4; ++n) b[n] = Bs[k][tx * 4 + n];
#pragma unroll
            for (int m = 0; m < 4; ++m)
#pragma unroll
                for (int n = 0; n < 4; ++n) acc[m][n] += a[m] * b[n];
        }
        __syncthreads();
    }

#pragma unroll
    for (int m = 0; m < 4; ++m) {
        int r = rowBase + ty * 4 + m;
        if (r < M) {
#pragma unroll
            for (int n = 0; n < 4; ++n)
                C[(size_t)r * N + colBase + tx * 4 + n] = acc[m][n];
        }
    }
}

// ---------------- aggregation ----------------
// agg[n,d] = dis[n]^2 * hw[n,d] + bias[d]   (self-loop term + bias)
__global__ void agg_init(const float* __restrict__ hw, float* __restrict__ agg,
                         const float* __restrict__ dis, const float* __restrict__ bias,
                         int D) {
    size_t i = (size_t)blockIdx.x * blockDim.x + threadIdx.x;
    size_t tot = (size_t)NN * D;
    if (i >= tot) return;
    int n = (int)(i / D);
    int d = (int)(i - (size_t)n * D);
    float w = dis[n];
    agg[i] = w * w * hw[i] + bias[d];
}

// scatter-add over edges: agg[dst] += dis[src]*dis[dst] * hw[src]
__global__ void agg_edges(const float* __restrict__ hw, float* __restrict__ agg,
                          const int* __restrict__ ei, const float* __restrict__ dis,
                          int D, int tpe) {
    long long tid = (long long)blockIdx.x * blockDim.x + threadIdx.x;
    long long tot = (long long)EE * tpe;
    if (tid >= tot) return;
    int e  = (int)(tid / tpe);
    int dq = (int)(tid % tpe) * 4;
    int s = ei[e];
    int t = ei[EE + e];
    float w = dis[s] * dis[t];
    float4 v = *reinterpret_cast<const float4*>(&hw[(size_t)s * D + dq]);
    float* ap = &agg[(size_t)t * D + dq];
    atomicAdd(ap + 0, w * v.x);
    atomicAdd(ap + 1, w * v.y);
    atomicAdd(ap + 2, w * v.z);
    atomicAdd(ap + 3, w * v.w);
}

// ---------------- batchnorm over node axis ----------------
__global__ void bn_stats(const float* __restrict__ h, float* __restrict__ stats, int D) {
    int d = blockIdx.x * blockDim.x + threadIdx.x;
    if (d >= D) return;
    float s = 0.f, ss = 0.f;
    for (int n = blockIdx.y; n < NN; n += gridDim.y) {
        float v = h[(size_t)n * D + d];
        s += v;
        ss += v * v;
    }
    atomicAdd(&stats[d], s);
    atomicAdd(&stats[D + d], ss);
}

__global__ void bn_apply(float* __restrict__ h, const float* __restrict__ stats,
                         const float* __restrict__ gamma, const float* __restrict__ beta,
                         int D, int do_relu) {
    size_t i = (size_t)blockIdx.x * blockDim.x + threadIdx.x;
    size_t tot = (size_t)NN * D;
    if (i >= tot) return;
    int d = (int)(i % (size_t)D);
    float mean = stats[d] * (1.0f / NN);
    float var  = stats[D + d] * (1.0f / NN) - mean * mean;
    float v = (h[i] - mean) * rsqrtf(var + BN_EPS) * gamma[d] + beta[d];
    h[i] = do_relu ? fmaxf(v, 0.f) : v;
}

// ---------------- pooling ----------------
__global__ void find_starts(const int* __restrict__ batch, int* __restrict__ start) {
    int n = blockIdx.x * blockDim.x + threadIdx.x;
    if (n >= NN) return;
    int bc = batch[n];
    int bp = (n == 0) ? -1 : batch[n - 1];
    for (int g = bp + 1; g <= bc; ++g) start[g] = n;
    if (n == NN - 1) {
        for (int g = bc + 1; g <= BB; ++g) start[g] = NN;
    }
}

// one block per graph, 128 threads (one per channel)
__global__ void pool_kernel(const float* __restrict__ h, const int* __restrict__ start,
                            float* __restrict__ pool) {
    int b = blockIdx.x;
    int d = threadIdx.x;
    int s0 = start[b], s1 = start[b + 1];
    float sum = 0.f;
    float mx = -3.402823466e+38f;
    for (int n = s0; n < s1; ++n) {
        float v = h[(size_t)n * 128 + d];
        sum += v;
        mx = fmaxf(mx, v);
    }
    float cnt = fmaxf((float)(s1 - s0), 1.0f);
    pool[b * 256 + d] = sum / cnt;
    pool[b * 256 + 128 + d] = mx;
}

// ---------------- classifier (single block) ----------------
__global__ __launch_bounds__(256) void classifier_kernel(
        const float* __restrict__ pool,
        const float* __restrict__ Wc1, const float* __restrict__ bc1,
        const float* __restrict__ gc, const float* __restrict__ bec,
        const float* __restrict__ Wc2, const float* __restrict__ bc2,
        float* __restrict__ out) {
    __shared__ float hc[64][65];
    __shared__ float cmean[64];
    __shared__ float crstd[64];
    int tid = threadIdx.x;

    // hc = relu(pool @ Wc1 + bc1)   [64 x 64]
    for (int i = tid; i < 64 * 64; i += 256) {
        int r = i / 64, c = i % 64;
        float acc = bc1[c];
        for (int k = 0; k < 256; ++k)
            acc += pool[r * 256 + k] * Wc1[k * 64 + c];
        hc[r][c] = fmaxf(acc, 0.f);
    }
    __syncthreads();

    // batchnorm stats over 64 rows
    if (tid < 64) {
        float s = 0.f, ss = 0.f;
        for (int r = 0; r < 64; ++r) {
            float v = hc[r][tid];
            s += v;
            ss += v * v;
        }
        float m = s * (1.0f / 64.0f);
        float var = ss * (1.0f / 64.0f) - m * m;
        cmean[tid] = m;
        crstd[tid] = rsqrtf(var + BN_EPS);
    }
    __syncthreads();

    // logits = BN(hc) @ Wc2 + bc2   [64 x 2]
    if (tid < 128) {
        int r = tid / 2, k = tid % 2;
        float acc = bc2[k];
        for (int c = 0; c < 64; ++c) {
            float v = (hc[r][c] - cmean[c]) * crstd[c] * gc[c] + bec[c];
            acc += v * Wc2[c * 2 + k];
        }
        out[r * 2 + k] = acc;
    }
}

// ---------------- launch ----------------
extern "C" void kernel_launch(void* const* d_in, const int* in_sizes, int n_in,
                              void* d_out, int out_size, void* d_ws, size_t ws_size,
                              hipStream_t stream) {
    const float* x     = (const float*)d_in[0];
    const int*   ei    = (const int*)d_in[1];
    const int*   batch = (const int*)d_in[2];
    const float* W[3]  = {(const float*)d_in[3], (const float*)d_in[7], (const float*)d_in[11]};
    const float* bb[3] = {(const float*)d_in[4], (const float*)d_in[8], (const float*)d_in[12]};
    const float* gm[3] = {(const float*)d_in[5], (const float*)d_in[9], (const float*)d_in[13]};
    const float* bt[3] = {(const float*)d_in[6], (const float*)d_in[10], (const float*)d_in[14]};
    const float* Wc1 = (const float*)d_in[15];
    const float* bc1 = (const float*)d_in[16];
    const float* gc  = (const float*)d_in[17];
    const float* bec = (const float*)d_in[18];
    const float* Wc2 = (const float*)d_in[19];
    const float* bc2 = (const float*)d_in[20];
    float* out = (float*)d_out;

    // workspace carve-up
    float* bufA  = (float*)d_ws;                       // N*512
    float* bufB  = bufA + (size_t)NN * 512;            // N*512
    float* deg   = bufB + (size_t)NN * 512;            // N
    float* dis   = deg + NN;                           // N
    float* stats = dis + NN;                           // 1024
    float* pool  = stats + 1024;                       // B*256
    int*   start = (int*)(pool + BB * 256);            // B+1

    // degree + rsqrt
    fill_f32<<<(NN + 255) / 256, 256, 0, stream>>>(deg, NN, 1.0f);
    deg_edges<<<(EE + 255) / 256, 256, 0, stream>>>(ei, deg);
    rsqrt_k<<<(NN + 255) / 256, 256, 0, stream>>>(deg, dis);

    const int dims[4] = {768, 512, 256, 128};
    const float* hin = x;
    float* hw  = bufA;
    float* agg = bufB;

    for (int l = 0; l < 3; ++l) {
        int K = dims[l], D = dims[l + 1];

        dim3 gg(D / 64, (NN + 63) / 64);
        gemm_f32<<<gg, 256, 0, stream>>>(hin, W[l], hw, NN, K, D);

        size_t tot = (size_t)NN * D;
        agg_init<<<(int)((tot + 255) / 256), 256, 0, stream>>>(hw, agg, dis, bb[l], D);

        int tpe = D / 4;
        long long etot = (long long)EE * tpe;
        agg_edges<<<(int)((etot + 255) / 256), 256, 0, stream>>>(hw, agg, ei, dis, D, tpe);

        fill_f32<<<(2 * D + 255) / 256, 256, 0, stream>>>(stats, 2 * D, 0.0f);
        bn_stats<<<dim3((D + 255) / 256, 256), 256, 0, stream>>>(agg, stats, D);
        bn_apply<<<(int)((tot + 255) / 256), 256, 0, stream>>>(agg, stats, gm[l], bt[l], D, l < 2 ? 1 : 0);

        hin = agg;   // next layer reads aggregated output (bufB); gemm writes bufA
    }

    find_starts<<<(NN + 255) / 256, 256, 0, stream>>>(batch, start);
    pool_kernel<<<BB, 128, 0, stream>>>(bufB, start, pool);
    classifier_kernel<<<1, 256, 0, stream>>>(pool, Wc1, bc1, gc, bec, Wc2, bc2, out);
}

// Round 2
// 1686.459 us; speedup vs baseline: 3.6347x; 3.6347x over previous
//
#include <hip/hip_runtime.h>
#include <cstddef>

#define NN 50000
#define EE 400000
#define BB 64
#define BN_EPS 1e-5f

// ---------------- utility ----------------
__global__ void fill_f32(float* __restrict__ p, int n, float v) {
    int i = blockIdx.x * blockDim.x + threadIdx.x;
    if (i < n) p[i] = v;
}

__global__ void fill_i32(int* __restrict__ p, int n, int v) {
    int i = blockIdx.x * blockDim.x + threadIdx.x;
    if (i < n) p[i] = v;
}

// integer in-degree (edges only; self-loop added in rsqrt)
__global__ void deg_edges(const int* __restrict__ ei, int* __restrict__ deg) {
    int e = blockIdx.x * blockDim.x + threadIdx.x;
    if (e < EE) atomicAdd(&deg[ei[EE + e]], 1);
}

__global__ void rsqrt_k(const int* __restrict__ deg, float* __restrict__ dis) {
    int i = blockIdx.x * blockDim.x + threadIdx.x;
    if (i < NN) dis[i] = rsqrtf((float)deg[i] + 1.0f);
}

// ---------------- CSR build: prefix scan of degrees ----------------
__global__ __launch_bounds__(256) void scan_block(const int* __restrict__ deg,
                                                  int* __restrict__ rowptr,
                                                  int* __restrict__ bsum) {
    __shared__ int tmp[256];
    int tid = threadIdx.x;
    int i = blockIdx.x * 256 + tid;
    int v = (i < NN) ? deg[i] : 0;
    tmp[tid] = v;
    __syncthreads();
#pragma unroll
    for (int off = 1; off < 256; off <<= 1) {
        int t = (tid >= off) ? tmp[tid - off] : 0;
        __syncthreads();
        tmp[tid] += t;
        __syncthreads();
    }
    if (i < NN) rowptr[i] = tmp[tid] - v;       // exclusive (local)
    if (tid == 255) bsum[blockIdx.x] = tmp[255];
}

__global__ __launch_bounds__(256) void scan_sums(const int* __restrict__ bsum,
                                                 int* __restrict__ boff, int nb) {
    __shared__ int tmp[256];
    int tid = threadIdx.x;
    int v = (tid < nb) ? bsum[tid] : 0;
    tmp[tid] = v;
    __syncthreads();
#pragma unroll
    for (int off = 1; off < 256; off <<= 1) {
        int t = (tid >= off) ? tmp[tid - off] : 0;
        __syncthreads();
        tmp[tid] += t;
        __syncthreads();
    }
    boff[tid] = tmp[tid] - v;                   // exclusive
}

__global__ void scan_fixup(int* __restrict__ rowptr, const int* __restrict__ boff) {
    int i = blockIdx.x * blockDim.x + threadIdx.x;
    if (i < NN) rowptr[i] += boff[i >> 8];
    if (i == 0) rowptr[NN] = EE;
}

__global__ void copy_i32(const int* __restrict__ a, int* __restrict__ b, int n) {
    int i = blockIdx.x * blockDim.x + threadIdx.x;
    if (i < n) b[i] = a[i];
}

__global__ void fill_csr(const int* __restrict__ ei, int* __restrict__ cursor,
                         int* __restrict__ csr_src) {
    int e = blockIdx.x * blockDim.x + threadIdx.x;
    if (e >= EE) return;
    int s = ei[e];
    int t = ei[EE + e];
    int pos = atomicAdd(&cursor[t], 1);
    csr_src[pos] = s;
}

// ---------------- fp32 tiled GEMM: C[M,N] = A[M,K] @ B[K,N] ----------------
__global__ __launch_bounds__(256) void gemm_f32(const float* __restrict__ A,
                                                const float* __restrict__ B,
                                                float* __restrict__ C,
                                                int M, int K, int N) {
    __shared__ float As[16][64 + 1];
    __shared__ float Bs[16][64];
    const int tid = threadIdx.x;
    const int tx = tid % 16;
    const int ty = tid / 16;
    const int rowBase = blockIdx.y * 64;
    const int colBase = blockIdx.x * 64;

    const int aRow = tid / 4;
    const int aK   = (tid % 4) * 4;
    const int bK   = tid / 16;
    const int bCol = (tid % 16) * 4;

    float acc[4][4] = {};

    for (int k0 = 0; k0 < K; k0 += 16) {
        int ar = rowBase + aRow;
        float4 av;
        if (ar < M) av = *reinterpret_cast<const float4*>(&A[(size_t)ar * K + k0 + aK]);
        else        av = make_float4(0.f, 0.f, 0.f, 0.f);
        As[aK + 0][aRow] = av.x;
        As[aK + 1][aRow] = av.y;
        As[aK + 2][aRow] = av.z;
        As[aK + 3][aRow] = av.w;

        float4 bv = *reinterpret_cast<const float4*>(&B[(size_t)(k0 + bK) * N + colBase + bCol]);
        *reinterpret_cast<float4*>(&Bs[bK][bCol]) = bv;

        __syncthreads();
#pragma unroll
        for (int k = 0; k < 16; ++k) {
            float a[4], b[4];
#pragma unroll
            for (int m = 0; m < 4; ++m) a[m] = As[k][ty * 4 + m];
#pragma unroll
            for (int n = 0; n < 4; ++n) b[n] = Bs[k][tx * 4 + n];
#pragma unroll
            for (int m = 0; m < 4; ++m)
#pragma unroll
                for (int n = 0; n < 4; ++n) acc[m][n] += a[m] * b[n];
        }
        __syncthreads();
    }

#pragma unroll
    for (int m = 0; m < 4; ++m) {
        int r = rowBase + ty * 4 + m;
        if (r < M) {
#pragma unroll
            for (int n = 0; n < 4; ++n)
                C[(size_t)r * N + colBase + tx * 4 + n] = acc[m][n];
        }
    }
}

// ---------------- gather aggregation (no atomics) ----------------
// agg[n,d] = dis[n]^2*hw[n,d] + bias[d] + sum_{e in CSR[n]} dis[src]*dis[n]*hw[src,d]
__global__ __launch_bounds__(256) void agg_gather(const float* __restrict__ hw,
                                                  float* __restrict__ agg,
                                                  const int* __restrict__ rowptr,
                                                  const int* __restrict__ csr_src,
                                                  const float* __restrict__ dis,
                                                  const float* __restrict__ bias,
                                                  int D) {
    const int tpn = D >> 2;                 // threads per node (float4 each)
    const int npb = 256 / tpn;              // nodes per block
    const int local = threadIdx.x / tpn;
    const int lane = threadIdx.x % tpn;
    const int n = blockIdx.x * npb + local;
    if (n >= NN) return;
    const int dq = lane * 4;

    float din = dis[n];
    float4 self = *reinterpret_cast<const float4*>(&hw[(size_t)n * D + dq]);
    float4 bsv  = *reinterpret_cast<const float4*>(&bias[dq]);
    float4 acc;
    float w0 = din * din;
    acc.x = w0 * self.x + bsv.x;
    acc.y = w0 * self.y + bsv.y;
    acc.z = w0 * self.z + bsv.z;
    acc.w = w0 * self.w + bsv.w;

    int s0 = rowptr[n], s1 = rowptr[n + 1];
    for (int e = s0; e < s1; ++e) {
        int s = csr_src[e];
        float w = din * dis[s];
        float4 v = *reinterpret_cast<const float4*>(&hw[(size_t)s * D + dq]);
        acc.x += w * v.x;
        acc.y += w * v.y;
        acc.z += w * v.z;
        acc.w += w * v.w;
    }
    *reinterpret_cast<float4*>(&agg[(size_t)n * D + dq]) = acc;
}

// ---------------- batchnorm over node axis ----------------
__global__ void bn_stats(const float* __restrict__ h, float* __restrict__ stats, int D) {
    int d = blockIdx.x * blockDim.x + threadIdx.x;
    if (d >= D) return;
    float s = 0.f, ss = 0.f;
    for (int n = blockIdx.y; n < NN; n += gridDim.y) {
        float v = h[(size_t)n * D + d];
        s += v;
        ss += v * v;
    }
    atomicAdd(&stats[d], s);
    atomicAdd(&stats[D + d], ss);
}

__global__ void bn_apply(float* __restrict__ h, const float* __restrict__ stats,
                         const float* __restrict__ gamma, const float* __restrict__ beta,
                         int D, int do_relu) {
    size_t i = (size_t)blockIdx.x * blockDim.x + threadIdx.x;
    size_t tot = (size_t)NN * D;
    if (i >= tot) return;
    int d = (int)(i % (size_t)D);
    float mean = stats[d] * (1.0f / NN);
    float var  = stats[D + d] * (1.0f / NN) - mean * mean;
    float v = (h[i] - mean) * rsqrtf(var + BN_EPS) * gamma[d] + beta[d];
    h[i] = do_relu ? fmaxf(v, 0.f) : v;
}

// ---------------- pooling ----------------
__global__ void find_starts(const int* __restrict__ batch, int* __restrict__ start) {
    int n = blockIdx.x * blockDim.x + threadIdx.x;
    if (n >= NN) return;
    int bc = batch[n];
    int bp = (n == 0) ? -1 : batch[n - 1];
    for (int g = bp + 1; g <= bc; ++g) start[g] = n;
    if (n == NN - 1) {
        for (int g = bc + 1; g <= BB; ++g) start[g] = NN;
    }
}

__global__ void pool_kernel(const float* __restrict__ h, const int* __restrict__ start,
                            float* __restrict__ pool) {
    int b = blockIdx.x;
    int d = threadIdx.x;
    int s0 = start[b], s1 = start[b + 1];
    float sum = 0.f;
    float mx = -3.402823466e+38f;
    for (int n = s0; n < s1; ++n) {
        float v = h[(size_t)n * 128 + d];
        sum += v;
        mx = fmaxf(mx, v);
    }
    float cnt = fmaxf((float)(s1 - s0), 1.0f);
    pool[b * 256 + d] = sum / cnt;
    pool[b * 256 + 128 + d] = mx;
}

// ---------------- classifier (single block) ----------------
__global__ __launch_bounds__(256) void classifier_kernel(
        const float* __restrict__ pool,
        const float* __restrict__ Wc1, const float* __restrict__ bc1,
        const float* __restrict__ gc, const float* __restrict__ bec,
        const float* __restrict__ Wc2, const float* __restrict__ bc2,
        float* __restrict__ out) {
    __shared__ float hc[64][65];
    __shared__ float cmean[64];
    __shared__ float crstd[64];
    int tid = threadIdx.x;

    for (int i = tid; i < 64 * 64; i += 256) {
        int r = i / 64, c = i % 64;
        float acc = bc1[c];
        for (int k = 0; k < 256; ++k)
            acc += pool[r * 256 + k] * Wc1[k * 64 + c];
        hc[r][c] = fmaxf(acc, 0.f);
    }
    __syncthreads();

    if (tid < 64) {
        float s = 0.f, ss = 0.f;
        for (int r = 0; r < 64; ++r) {
            float v = hc[r][tid];
            s += v;
            ss += v * v;
        }
        float m = s * (1.0f / 64.0f);
        float var = ss * (1.0f / 64.0f) - m * m;
        cmean[tid] = m;
        crstd[tid] = rsqrtf(var + BN_EPS);
    }
    __syncthreads();

    if (tid < 128) {
        int r = tid / 2, k = tid % 2;
        float acc = bc2[k];
        for (int c = 0; c < 64; ++c) {
            float v = (hc[r][c] - cmean[c]) * crstd[c] * gc[c] + bec[c];
            acc += v * Wc2[c * 2 + k];
        }
        out[r * 2 + k] = acc;
    }
}

// ---------------- launch ----------------
extern "C" void kernel_launch(void* const* d_in, const int* in_sizes, int n_in,
                              void* d_out, int out_size, void* d_ws, size_t ws_size,
                              hipStream_t stream) {
    const float* x     = (const float*)d_in[0];
    const int*   ei    = (const int*)d_in[1];
    const int*   batch = (const int*)d_in[2];
    const float* W[3]  = {(const float*)d_in[3], (const float*)d_in[7], (const float*)d_in[11]};
    const float* bb[3] = {(const float*)d_in[4], (const float*)d_in[8], (const float*)d_in[12]};
    const float* gm[3] = {(const float*)d_in[5], (const float*)d_in[9], (const float*)d_in[13]};
    const float* bt[3] = {(const float*)d_in[6], (const float*)d_in[10], (const float*)d_in[14]};
    const float* Wc1 = (const float*)d_in[15];
    const float* bc1 = (const float*)d_in[16];
    const float* gc  = (const float*)d_in[17];
    const float* bec = (const float*)d_in[18];
    const float* Wc2 = (const float*)d_in[19];
    const float* bc2 = (const float*)d_in[20];
    float* out = (float*)d_out;

    // workspace carve-up
    float* bufA  = (float*)d_ws;                       // N*512
    float* bufB  = bufA + (size_t)NN * 512;            // N*512
    float* dis   = bufB + (size_t)NN * 512;            // N
    float* stats = dis + NN;                           // 1024
    float* pool  = stats + 1024;                       // B*256
    int*   deg_i   = (int*)(pool + BB * 256);          // N
    int*   rowptr  = deg_i + NN;                       // N+1
    int*   cursor  = rowptr + NN + 1;                  // N
    int*   bsum    = cursor + NN;                      // 256
    int*   boff    = bsum + 256;                       // 256
    int*   csr_src = boff + 256;                       // E
    int*   start   = csr_src + EE;                     // B+1

    const int nb = (NN + 255) / 256;   // 196 scan blocks

    // degree (int) + dis
    fill_i32<<<nb, 256, 0, stream>>>(deg_i, NN, 0);
    deg_edges<<<(EE + 255) / 256, 256, 0, stream>>>(ei, deg_i);
    rsqrt_k<<<nb, 256, 0, stream>>>(deg_i, dis);

    // CSR build
    scan_block<<<nb, 256, 0, stream>>>(deg_i, rowptr, bsum);
    scan_sums<<<1, 256, 0, stream>>>(bsum, boff, nb);
    scan_fixup<<<nb, 256, 0, stream>>>(rowptr, boff);
    copy_i32<<<nb, 256, 0, stream>>>(rowptr, cursor, NN);
    fill_csr<<<(EE + 255) / 256, 256, 0, stream>>>(ei, cursor, csr_src);

    const int dims[4] = {768, 512, 256, 128};
    const float* hin = x;
    float* hw  = bufA;
    float* agg = bufB;

    for (int l = 0; l < 3; ++l) {
        int K = dims[l], D = dims[l + 1];

        dim3 gg(D / 64, (NN + 63) / 64);
        gemm_f32<<<gg, 256, 0, stream>>>(hin, W[l], hw, NN, K, D);

        int tpn = D / 4;
        int npb = 256 / tpn;
        agg_gather<<<(NN + npb - 1) / npb, 256, 0, stream>>>(hw, agg, rowptr, csr_src,
                                                             dis, bb[l], D);

        size_t tot = (size_t)NN * D;
        fill_f32<<<(2 * D + 255) / 256, 256, 0, stream>>>(stats, 2 * D, 0.0f);
        bn_stats<<<dim3((D + 255) / 256, 256), 256, 0, stream>>>(agg, stats, D);
        bn_apply<<<(int)((tot + 255) / 256), 256, 0, stream>>>(agg, stats, gm[l], bt[l], D, l < 2 ? 1 : 0);

        hin = agg;
    }

    find_starts<<<nb, 256, 0, stream>>>(batch, start);
    pool_kernel<<<BB, 128, 0, stream>>>(bufB, start, pool);
    classifier_kernel<<<1, 256, 0, stream>>>(pool, Wc1, bc1, gc, bec, Wc2, bc2, out);
}

// Round 5
// 1195.378 us; speedup vs baseline: 5.1279x; 1.4108x over previous
//
#include <hip/hip_runtime.h>
#include <cstddef>

#define NN 50000
#define EE 400000
#define BB 64
#define MP 50048            // padded rows: 391 * 128
#define BN_EPS 1e-5f

typedef __attribute__((ext_vector_type(8))) short s16x8;
typedef __attribute__((ext_vector_type(4))) float f32x4;

#define GLOAD_LDS16(g, l) __builtin_amdgcn_global_load_lds( \
    (const __attribute__((address_space(1))) void*)(g),     \
    (__attribute__((address_space(3))) void*)(l), 16, 0, 0)

// ---------------- utility ----------------
__global__ void fill_f32(float* __restrict__ p, int n, float v) {
    int i = blockIdx.x * blockDim.x + threadIdx.x;
    if (i < n) p[i] = v;
}

__global__ void fill_i32(int* __restrict__ p, int n, int v) {
    int i = blockIdx.x * blockDim.x + threadIdx.x;
    if (i < n) p[i] = v;
}

__global__ void deg_edges(const int* __restrict__ ei, int* __restrict__ deg) {
    int e = blockIdx.x * blockDim.x + threadIdx.x;
    if (e < EE) atomicAdd(&deg[ei[EE + e]], 1);
}

__global__ void rsqrt_k(const int* __restrict__ deg, float* __restrict__ dis) {
    int i = blockIdx.x * blockDim.x + threadIdx.x;
    if (i < NN) dis[i] = rsqrtf((float)deg[i] + 1.0f);
}

// W [K][N] fp32 -> Wt packed [N][K] u32 (hi bf16 bits in top 16, lo bf16 bits in bottom 16)
__global__ void cvt_wt_pack(const float* __restrict__ W, unsigned int* __restrict__ Wt,
                            int K, int N) {
    int i = blockIdx.x * blockDim.x + threadIdx.x;
    if (i >= K * N) return;
    int k = i / N, n = i % N;
    float f = W[i];
    unsigned int fb = __float_as_uint(f);
    unsigned int hif = fb & 0xFFFF0000u;
    float lo = f - __uint_as_float(hif);
    Wt[(size_t)n * K + k] = hif | (__float_as_uint(lo) >> 16);
}

// ---------------- CSR build ----------------
__global__ __launch_bounds__(256) void scan_block(const int* __restrict__ deg,
                                                  int* __restrict__ rowptr,
                                                  int* __restrict__ bsum) {
    __shared__ int tmp[256];
    int tid = threadIdx.x;
    int i = blockIdx.x * 256 + tid;
    int v = (i < NN) ? deg[i] : 0;
    tmp[tid] = v;
    __syncthreads();
#pragma unroll
    for (int off = 1; off < 256; off <<= 1) {
        int t = (tid >= off) ? tmp[tid - off] : 0;
        __syncthreads();
        tmp[tid] += t;
        __syncthreads();
    }
    if (i < NN) rowptr[i] = tmp[tid] - v;
    if (tid == 255) bsum[blockIdx.x] = tmp[255];
}

__global__ __launch_bounds__(256) void scan_sums(const int* __restrict__ bsum,
                                                 int* __restrict__ boff, int nb) {
    __shared__ int tmp[256];
    int tid = threadIdx.x;
    int v = (tid < nb) ? bsum[tid] : 0;
    tmp[tid] = v;
    __syncthreads();
#pragma unroll
    for (int off = 1; off < 256; off <<= 1) {
        int t = (tid >= off) ? tmp[tid - off] : 0;
        __syncthreads();
        tmp[tid] += t;
        __syncthreads();
    }
    boff[tid] = tmp[tid] - v;
}

__global__ void scan_fixup(int* __restrict__ rowptr, const int* __restrict__ boff) {
    int i = blockIdx.x * blockDim.x + threadIdx.x;
    if (i < NN) rowptr[i] += boff[i >> 8];
    if (i == 0) rowptr[NN] = EE;
}

__global__ void copy_i32(const int* __restrict__ a, int* __restrict__ b, int n) {
    int i = blockIdx.x * blockDim.x + threadIdx.x;
    if (i < n) b[i] = a[i];
}

__global__ void fill_csr(const int* __restrict__ ei, int* __restrict__ cursor,
                         int* __restrict__ csr_src) {
    int e = blockIdx.x * blockDim.x + threadIdx.x;
    if (e >= EE) return;
    int s = ei[e];
    int t = ei[EE + e];
    int pos = atomicAdd(&cursor[t], 1);
    csr_src[pos] = s;
}

// ---------------- split helpers (mask/shift only — no perm intrinsics) ----------------
// packed u32 p = (hi bf16 bits << 16) | (lo bf16 bits)
static __device__ __forceinline__ void unpack_pk(const uint4& u0, const uint4& u1,
                                                 s16x8& h, s16x8& l) {
    unsigned int p[8] = {u0.x, u0.y, u0.z, u0.w, u1.x, u1.y, u1.z, u1.w};
    union { s16x8 v; unsigned int u[4]; } H, L;
#pragma unroll
    for (int k = 0; k < 4; ++k) {
        H.u[k] = (p[2 * k + 1] & 0xFFFF0000u) | (p[2 * k] >> 16);
        L.u[k] = (p[2 * k + 1] << 16) | (p[2 * k] & 0xFFFFu);
    }
    h = H.v; l = L.v;
}

// 8 consecutive fp32 -> hi bf16 (truncate) + lo bf16 (round of residual)
static __device__ __forceinline__ void unpack_f32(const uint4& u0, const uint4& u1,
                                                  s16x8& h, s16x8& l) {
    unsigned int e[8] = {u0.x, u0.y, u0.z, u0.w, u1.x, u1.y, u1.z, u1.w};
    unsigned int hi[8], lo[8];
#pragma unroll
    for (int j = 0; j < 8; ++j) {
        hi[j] = e[j] & 0xFFFF0000u;
        float lf = __uint_as_float(e[j]) - __uint_as_float(hi[j]);
        lo[j] = __float_as_uint(lf);
    }
    union { s16x8 v; unsigned int u[4]; } H, L;
#pragma unroll
    for (int k = 0; k < 4; ++k) {
        H.u[k] = (hi[2 * k + 1]) | (hi[2 * k] >> 16);
        L.u[k] = (lo[2 * k + 1] & 0xFFFF0000u) | (lo[2 * k] >> 16);
    }
    h = H.v; l = L.v;
}

// ------ split-bf16 3-MFMA GEMM: C[MP,N] = A[MP,K] @ Wt[N,K]^T, fp32 in / fp32 out ------
// 128x128 tile, BK=32, 4 waves (2x2). Linear LDS staging (no swizzle — correctness round).
// A rows clamped to NN-1 (pad rows read valid data, outputs unused).
__global__ __launch_bounds__(256) void gemm_split3(const float* __restrict__ A,
                                                   const unsigned int* __restrict__ Bt,
                                                   float* __restrict__ C,
                                                   int K, int N) {
    __shared__ unsigned int As[128 * 32];   // [row][k]   fp32 bits
    __shared__ unsigned int Bs[128 * 32];   // [col][k]   packed split bf16
    const int tid = threadIdx.x;
    const int w  = tid >> 6;
    const int lw = tid & 63;
    const int lo = lw & 15;
    const int hi = lw >> 4;
    const int wr = w >> 1, wc = w & 1;
    const int rowBase = blockIdx.y * 128;
    const int colBase = blockIdx.x * 128;

    const int srow = w * 8 + (lw >> 3);     // staging row 0..31 (+ i*32)
    const int sc   = (lw & 7) * 4;          // staging u32 col

    f32x4 acc[4][4];
#pragma unroll
    for (int m = 0; m < 4; ++m)
#pragma unroll
        for (int n = 0; n < 4; ++n) acc[m][n] = (f32x4){0.f, 0.f, 0.f, 0.f};

    for (int k0 = 0; k0 < K; k0 += 32) {
#pragma unroll
        for (int i = 0; i < 4; ++i) {
            int r = i * 32 + srow;
            int gr = rowBase + r;
            gr = (gr < NN) ? gr : (NN - 1);
            GLOAD_LDS16((const unsigned int*)A + (size_t)gr * K + k0 + sc,
                        (char*)As + i * 4096 + w * 1024);
            GLOAD_LDS16(Bt + (size_t)(colBase + r) * K + k0 + sc,
                        (char*)Bs + i * 4096 + w * 1024);
        }
        __syncthreads();

        s16x8 ah[4], al[4], bh[4], bl[4];
#pragma unroll
        for (int m = 0; m < 4; ++m) {
            int r = wr * 64 + m * 16 + lo;
            uint4 u0 = *(const uint4*)&As[r * 32 + hi * 8];
            uint4 u1 = *(const uint4*)&As[r * 32 + hi * 8 + 4];
            unpack_f32(u0, u1, ah[m], al[m]);
        }
#pragma unroll
        for (int n = 0; n < 4; ++n) {
            int r = wc * 64 + n * 16 + lo;
            uint4 u0 = *(const uint4*)&Bs[r * 32 + hi * 8];
            uint4 u1 = *(const uint4*)&Bs[r * 32 + hi * 8 + 4];
            unpack_pk(u0, u1, bh[n], bl[n]);
        }
#pragma unroll
        for (int m = 0; m < 4; ++m)
#pragma unroll
            for (int n = 0; n < 4; ++n) {
                acc[m][n] = __builtin_amdgcn_mfma_f32_16x16x32_bf16(ah[m], bh[n], acc[m][n], 0, 0, 0);
                acc[m][n] = __builtin_amdgcn_mfma_f32_16x16x32_bf16(ah[m], bl[n], acc[m][n], 0, 0, 0);
                acc[m][n] = __builtin_amdgcn_mfma_f32_16x16x32_bf16(al[m], bh[n], acc[m][n], 0, 0, 0);
            }
        __syncthreads();
    }

#pragma unroll
    for (int m = 0; m < 4; ++m) {
        int row0 = rowBase + wr * 64 + m * 16 + hi * 4;
#pragma unroll
        for (int n = 0; n < 4; ++n) {
            int col = colBase + wc * 64 + n * 16 + lo;
#pragma unroll
            for (int j = 0; j < 4; ++j)
                C[(size_t)(row0 + j) * N + col] = acc[m][n][j];
        }
    }
}

// ---------------- gather aggregation (fp32, no atomics — r2 verbatim) ----------------
__global__ __launch_bounds__(256) void agg_gather(const float* __restrict__ hw,
                                                  float* __restrict__ agg,
                                                  const int* __restrict__ rowptr,
                                                  const int* __restrict__ csr_src,
                                                  const float* __restrict__ dis,
                                                  const float* __restrict__ bias,
                                                  int D) {
    const int tpn = D >> 2;
    const int npb = 256 / tpn;
    const int local = threadIdx.x / tpn;
    const int lane = threadIdx.x % tpn;
    const int n = blockIdx.x * npb + local;
    if (n >= NN) return;
    const int dq = lane * 4;

    float din = dis[n];
    float4 self = *reinterpret_cast<const float4*>(&hw[(size_t)n * D + dq]);
    float4 bsv  = *reinterpret_cast<const float4*>(&bias[dq]);
    float4 acc;
    float w0 = din * din;
    acc.x = w0 * self.x + bsv.x;
    acc.y = w0 * self.y + bsv.y;
    acc.z = w0 * self.z + bsv.z;
    acc.w = w0 * self.w + bsv.w;

    int s0 = rowptr[n], s1 = rowptr[n + 1];
    for (int e = s0; e < s1; ++e) {
        int s = csr_src[e];
        float w = din * dis[s];
        float4 v = *reinterpret_cast<const float4*>(&hw[(size_t)s * D + dq]);
        acc.x += w * v.x;
        acc.y += w * v.y;
        acc.z += w * v.z;
        acc.w += w * v.w;
    }
    *reinterpret_cast<float4*>(&agg[(size_t)n * D + dq]) = acc;
}

// ---------------- batchnorm (fp32, r2 verbatim) ----------------
__global__ void bn_stats(const float* __restrict__ h, float* __restrict__ stats, int D) {
    int d = blockIdx.x * blockDim.x + threadIdx.x;
    if (d >= D) return;
    float s = 0.f, ss = 0.f;
    for (int n = blockIdx.y; n < NN; n += gridDim.y) {
        float v = h[(size_t)n * D + d];
        s += v;
        ss += v * v;
    }
    atomicAdd(&stats[d], s);
    atomicAdd(&stats[D + d], ss);
}

__global__ void bn_apply(float* __restrict__ h, const float* __restrict__ stats,
                         const float* __restrict__ gamma, const float* __restrict__ beta,
                         int D, int do_relu) {
    size_t i = (size_t)blockIdx.x * blockDim.x + threadIdx.x;
    size_t tot = (size_t)NN * D;
    if (i >= tot) return;
    int d = (int)(i % (size_t)D);
    float mean = stats[d] * (1.0f / NN);
    float var  = stats[D + d] * (1.0f / NN) - mean * mean;
    float v = (h[i] - mean) * rsqrtf(var + BN_EPS) * gamma[d] + beta[d];
    h[i] = do_relu ? fmaxf(v, 0.f) : v;
}

// ---------------- pooling (r2 verbatim) ----------------
__global__ void find_starts(const int* __restrict__ batch, int* __restrict__ start) {
    int n = blockIdx.x * blockDim.x + threadIdx.x;
    if (n >= NN) return;
    int bc = batch[n];
    int bp = (n == 0) ? -1 : batch[n - 1];
    for (int g = bp + 1; g <= bc; ++g) start[g] = n;
    if (n == NN - 1) {
        for (int g = bc + 1; g <= BB; ++g) start[g] = NN;
    }
}

__global__ void pool_kernel(const float* __restrict__ h, const int* __restrict__ start,
                            float* __restrict__ pool) {
    int b = blockIdx.x;
    int d = threadIdx.x;
    int s0 = start[b], s1 = start[b + 1];
    float sum = 0.f;
    float mx = -3.402823466e+38f;
    for (int n = s0; n < s1; ++n) {
        float v = h[(size_t)n * 128 + d];
        sum += v;
        mx = fmaxf(mx, v);
    }
    float cnt = fmaxf((float)(s1 - s0), 1.0f);
    pool[b * 256 + d] = sum / cnt;
    pool[b * 256 + 128 + d] = mx;
}

// ---------------- classifier (r2 verbatim) ----------------
__global__ __launch_bounds__(256) void classifier_kernel(
        const float* __restrict__ pool,
        const float* __restrict__ Wc1, const float* __restrict__ bc1,
        const float* __restrict__ gc, const float* __restrict__ bec,
        const float* __restrict__ Wc2, const float* __restrict__ bc2,
        float* __restrict__ out) {
    __shared__ float hc[64][65];
    __shared__ float cmean[64];
    __shared__ float crstd[64];
    int tid = threadIdx.x;

    for (int i = tid; i < 64 * 64; i += 256) {
        int r = i / 64, c = i % 64;
        float acc = bc1[c];
        for (int k = 0; k < 256; ++k)
            acc += pool[r * 256 + k] * Wc1[k * 64 + c];
        hc[r][c] = fmaxf(acc, 0.f);
    }
    __syncthreads();

    if (tid < 64) {
        float s = 0.f, ss = 0.f;
        for (int r = 0; r < 64; ++r) {
            float v = hc[r][tid];
            s += v;
            ss += v * v;
        }
        float m = s * (1.0f / 64.0f);
        float var = ss * (1.0f / 64.0f) - m * m;
        cmean[tid] = m;
        crstd[tid] = rsqrtf(var + BN_EPS);
    }
    __syncthreads();

    if (tid < 128) {
        int r = tid / 2, k = tid % 2;
        float acc = bc2[k];
        for (int c = 0; c < 64; ++c) {
            float v = (hc[r][c] - cmean[c]) * crstd[c] * gc[c] + bec[c];
            acc += v * Wc2[c * 2 + k];
        }
        out[r * 2 + k] = acc;
    }
}

// ---------------- launch ----------------
extern "C" void kernel_launch(void* const* d_in, const int* in_sizes, int n_in,
                              void* d_out, int out_size, void* d_ws, size_t ws_size,
                              hipStream_t stream) {
    const float* x     = (const float*)d_in[0];
    const int*   ei    = (const int*)d_in[1];
    const int*   batch = (const int*)d_in[2];
    const float* W[3]  = {(const float*)d_in[3], (const float*)d_in[7], (const float*)d_in[11]};
    const float* bbv[3] = {(const float*)d_in[4], (const float*)d_in[8], (const float*)d_in[12]};
    const float* gm[3] = {(const float*)d_in[5], (const float*)d_in[9], (const float*)d_in[13]};
    const float* bt[3] = {(const float*)d_in[6], (const float*)d_in[10], (const float*)d_in[14]};
    const float* Wc1 = (const float*)d_in[15];
    const float* bc1 = (const float*)d_in[16];
    const float* gc  = (const float*)d_in[17];
    const float* bec = (const float*)d_in[18];
    const float* Wc2 = (const float*)d_in[19];
    const float* bc2 = (const float*)d_in[20];
    float* out = (float*)d_out;

    // workspace carve-up (~207 MB)
    char* p = (char*)d_ws;
    float* hw  = (float*)p;  p += (size_t)MP * 512 * 4;   // GEMM out (padded rows)
    float* agg = (float*)p;  p += (size_t)NN * 512 * 4;   // agg / h (in-place BN)
    unsigned int* Wt[3];
    Wt[0] = (unsigned int*)p; p += (size_t)512 * 768 * 4;
    Wt[1] = (unsigned int*)p; p += (size_t)256 * 512 * 4;
    Wt[2] = (unsigned int*)p; p += (size_t)128 * 256 * 4;
    float* dis   = (float*)p; p += (size_t)NN * 4;
    float* stats = (float*)p; p += 1024 * 4;
    float* pool  = (float*)p; p += (size_t)BB * 256 * 4;
    int* deg_i   = (int*)p; p += (size_t)NN * 4;
    int* rowptr  = (int*)p; p += (size_t)(NN + 1) * 4;
    int* cursor  = (int*)p; p += (size_t)NN * 4;
    int* bsum    = (int*)p; p += 256 * 4;
    int* boff    = (int*)p; p += 256 * 4;
    int* csr_src = (int*)p; p += (size_t)EE * 4;
    int* start   = (int*)p; p += (BB + 1) * 4;

    const int nb = (NN + 255) / 256;

    // weight split-pack (tiny)
    cvt_wt_pack<<<(768 * 512 + 255) / 256, 256, 0, stream>>>(W[0], Wt[0], 768, 512);
    cvt_wt_pack<<<(512 * 256 + 255) / 256, 256, 0, stream>>>(W[1], Wt[1], 512, 256);
    cvt_wt_pack<<<(256 * 128 + 255) / 256, 256, 0, stream>>>(W[2], Wt[2], 256, 128);

    // degree + dis + CSR
    fill_i32<<<nb, 256, 0, stream>>>(deg_i, NN, 0);
    deg_edges<<<(EE + 255) / 256, 256, 0, stream>>>(ei, deg_i);
    rsqrt_k<<<nb, 256, 0, stream>>>(deg_i, dis);
    scan_block<<<nb, 256, 0, stream>>>(deg_i, rowptr, bsum);
    scan_sums<<<1, 256, 0, stream>>>(bsum, boff, nb);
    scan_fixup<<<nb, 256, 0, stream>>>(rowptr, boff);
    copy_i32<<<nb, 256, 0, stream>>>(rowptr, cursor, NN);
    fill_csr<<<(EE + 255) / 256, 256, 0, stream>>>(ei, cursor, csr_src);

    const int dims[4] = {768, 512, 256, 128};
    const float* hin = x;

    for (int l = 0; l < 3; ++l) {
        int K = dims[l], D = dims[l + 1];

        dim3 gg(D / 128, MP / 128);
        gemm_split3<<<gg, 256, 0, stream>>>(hin, Wt[l], hw, K, D);

        int tpn = D / 4;
        int npb = 256 / tpn;
        agg_gather<<<(NN + npb - 1) / npb, 256, 0, stream>>>(hw, agg, rowptr, csr_src,
                                                             dis, bbv[l], D);

        fill_f32<<<(2 * D + 255) / 256, 256, 0, stream>>>(stats, 2 * D, 0.0f);
        bn_stats<<<dim3((D + 255) / 256, 256), 256, 0, stream>>>(agg, stats, D);
        size_t tot = (size_t)NN * D;
        bn_apply<<<(int)((tot + 255) / 256), 256, 0, stream>>>(agg, stats, gm[l], bt[l],
                                                               D, l < 2 ? 1 : 0);
        hin = agg;
    }

    find_starts<<<nb, 256, 0, stream>>>(batch, start);
    pool_kernel<<<BB, 128, 0, stream>>>(agg, start, pool);
    classifier_kernel<<<1, 256, 0, stream>>>(pool, Wc1, bc1, gc, bec, Wc2, bc2, out);
}